// Round 6
// baseline (482.925 us; speedup 1.0000x reference)
//
#include <hip/hip_runtime.h>
#include <hip/hip_bf16.h>
#include <hip/hip_cooperative_groups.h>

namespace cg = cooperative_groups;

#define NB 128
#define NQ 900
#define NT 256
#define NG 20
#define NR 15                 // pred rows per lane in match: 64*15 >= 900
#define FOCAL_BLOCKS 832
#define MATCH_BLOCKS 128
#define TOTAL_BLOCKS (FOCAL_BLOCKS + MATCH_BLOCKS)   // 960 <= 1024 @ 4 blocks/CU
#define FWAVES (FOCAL_BLOCKS * 4)                    // 3328 focal waves
#define NCHUNK 14400                                 // 115200 rows / 8 per chunk

// ws layout (floats): [0,3328) focal per-wave partials
//                     [3328,3456) bbox, [3456,3584) giou, [3584,3712) delta
#define WS_BB 3328
#define WS_GI 3456
#define WS_DL 3584

__device__ __forceinline__ float clamp01(float v) {
    return fminf(fmaxf(v, 0.0f), 1.0f);
}

__device__ __forceinline__ void ws_store(float* p, float v) {
    __hip_atomic_store(p, v, __ATOMIC_RELAXED, __HIP_MEMORY_SCOPE_AGENT);
}
__device__ __forceinline__ float ws_load(const float* p) {
    return __hip_atomic_load(p, __ATOMIC_RELAXED, __HIP_MEMORY_SCOPE_AGENT);
}

// focal(x, target=0) WITHOUT the 0.75 alpha (folded into finalize).
__device__ __forceinline__ float focal_neg_term(float x) {
    float ax  = fabsf(x);
    float em  = __expf(-ax);
    float a1  = 1.0f + em;
    float ce  = fmaxf(x, 0.0f) + __logf(a1);
    float inv = __builtin_amdgcn_rcpf(a1);
    float p   = (x >= 0.0f) ? inv : em * inv;
    return ce * p * p;
}

// focal(x,1) - focal(x,0), full alpha factors included.
__device__ __forceinline__ float focal_delta_term(float x) {
    float ax     = fabsf(x);
    float em     = __expf(-ax);
    float a1     = 1.0f + em;
    float lg     = __logf(a1);
    float ce0    = fmaxf(x, 0.0f) + lg;
    float ce1    = ce0 - x;
    float inv    = __builtin_amdgcn_rcpf(a1);
    float em_inv = em * inv;
    float p      = (x >= 0.0f) ? inv : em_inv;   // sigmoid(x)
    float omp    = (x >= 0.0f) ? em_inv : inv;   // 1 - p
    return 0.25f * ce1 * omp * omp - 0.75f * ce0 * p * p;
}

__device__ __forceinline__ float focal_row_sum4(float4 v) {
    return focal_neg_term(v.x) + focal_neg_term(v.y) +
           focal_neg_term(v.z) + focal_neg_term(v.w);
}

// ---------------------------------------------------------------------------
// Shared device paths (used by both the coop kernel and the fallback pair).
// ---------------------------------------------------------------------------
__device__ void focal_path(const float4* __restrict__ logits,
                           float* __restrict__ ws, int fblock) {
    const int lane = threadIdx.x & 63;
    const int gw   = (fblock * 256 + (int)threadIdx.x) >> 6;   // 0..FWAVES-1

    float sum = 0.0f;
    for (int c = gw; c < NCHUNK; c += FWAVES) {
        const float4* base = logits + (size_t)(c * 8) * (NT / 4) + lane;
        float4 v0 = base[0 * (NT / 4)];
        float4 v1 = base[1 * (NT / 4)];
        float4 v2 = base[2 * (NT / 4)];
        float4 v3 = base[3 * (NT / 4)];
        float4 v4 = base[4 * (NT / 4)];
        float4 v5 = base[5 * (NT / 4)];
        float4 v6 = base[6 * (NT / 4)];
        float4 v7 = base[7 * (NT / 4)];
        sum += focal_row_sum4(v0) + focal_row_sum4(v1) +
               focal_row_sum4(v2) + focal_row_sum4(v3) +
               focal_row_sum4(v4) + focal_row_sum4(v5) +
               focal_row_sum4(v6) + focal_row_sum4(v7);
    }
    #pragma unroll
    for (int off = 32; off > 0; off >>= 1) sum += __shfl_down(sum, off);
    if (lane == 0) ws_store(&ws[gw], sum);
}

__device__ void match_path(const float4* __restrict__ logits,
                           const float4* __restrict__ pred_boxes,
                           const float4* __restrict__ tgt_boxes,
                           const int2*   __restrict__ tokens,
                           float* __restrict__ ws,
                           float4* sbox, float* sarea, int b) {
    // All 256 threads stage pred boxes (xyxy + area) into LDS.
    for (int q = threadIdx.x; q < NQ; q += 256) {
        float4 pb = pred_boxes[b * NQ + q];
        float x1 = pb.x - 0.5f * pb.z, y1 = pb.y - 0.5f * pb.w;
        float x2 = pb.x + 0.5f * pb.z, y2 = pb.y + 0.5f * pb.w;
        sbox[q]  = make_float4(x1, y1, x2, y2);
        sarea[q] = (x2 - x1) * (y2 - y1);
    }
    __syncthreads();

    if (threadIdx.x >= 64) return;   // callers have no later block-wide syncs
    const int lane = threadIdx.x;
    int avail = (1 << NR) - 1;
    #pragma unroll
    for (int r = 0; r < NR; ++r)
        if (lane + 64 * r >= NQ) avail &= ~(1 << r);

    int my_q = 0;   // matched q for g == lane (lanes 0..19)
    for (int g = 0; g < NG; ++g) {
        float4 tb = tgt_boxes[b * NG + g];      // broadcast load
        float gx1 = tb.x - 0.5f * tb.z, gy1 = tb.y - 0.5f * tb.w;
        float gx2 = tb.x + 0.5f * tb.z, gy2 = tb.y + 0.5f * tb.w;
        float ga  = (gx2 - gx1) * (gy2 - gy1);
        float bv = -2.0f;
        int   bi = 0x7fffffff;
        #pragma unroll
        for (int r = 0; r < NR; ++r) {
            int q = lane + 64 * r;
            bool ok = (avail >> r) & 1;
            int qs = ok ? q : 0;               // safe LDS index
            float4 pbx = sbox[qs];
            float pa   = sarea[qs];
            float ix1 = fmaxf(pbx.x, gx1), iy1 = fmaxf(pbx.y, gy1);
            float ix2 = fminf(pbx.z, gx2), iy2 = fminf(pbx.w, gy2);
            float iw = fmaxf(ix2 - ix1, 0.0f), ih = fmaxf(iy2 - iy1, 0.0f);
            float inter = iw * ih;
            float v = inter / (pa + ga - inter);   // exact div, matches ref
            v = ok ? v : -1.0f;
            if (v > bv) { bv = v; bi = q; }        // strict >: first max per lane
        }
        #pragma unroll
        for (int off = 1; off < 64; off <<= 1) {
            float ov = __shfl_xor(bv, off);
            int   oi = __shfl_xor(bi, off);
            if (ov > bv || (ov == bv && oi < bi)) { bv = ov; bi = oi; }
        }
        if (lane == g) my_q = bi;
        if ((bi & 63) == lane) avail &= ~(1 << (bi >> 6));
    }

    // Epilogue: bbox L1 + GIoU + span correction for g = lane < 20.
    float lb = 0.0f, lgi = 0.0f, dl = 0.0f;
    if (lane < NG) {
        int g = lane, q = my_q;
        float4 pb = pred_boxes[b * NQ + q];
        float4 tb = tgt_boxes[b * NG + g];
        lb = fabsf(pb.x - tb.x) + fabsf(pb.y - tb.y) +
             fabsf(pb.z - tb.z) + fabsf(pb.w - tb.w);

        float mx1 = pb.x - 0.5f * pb.z, my1 = pb.y - 0.5f * pb.w;
        float mx2 = pb.x + 0.5f * pb.z, my2 = pb.y + 0.5f * pb.w;
        mx2 = fmaxf(mx2, mx1 + 1e-6f);  my2 = fmaxf(my2, my1 + 1e-6f);
        mx1 = clamp01(mx1); my1 = clamp01(my1);
        mx2 = clamp01(mx2); my2 = clamp01(my2);

        float gx1 = tb.x - 0.5f * tb.z, gy1 = tb.y - 0.5f * tb.w;
        float gx2 = tb.x + 0.5f * tb.z, gy2 = tb.y + 0.5f * tb.w;
        gx2 = fmaxf(gx2, gx1 + 1e-6f);  gy2 = fmaxf(gy2, gy1 + 1e-6f);
        gx1 = clamp01(gx1); gy1 = clamp01(gy1);
        gx2 = clamp01(gx2); gy2 = clamp01(gy2);

        float a1 = (mx2 - mx1) * (my2 - my1);
        float a2 = (gx2 - gx1) * (gy2 - gy1);
        float ix1 = fmaxf(mx1, gx1), iy1 = fmaxf(my1, gy1);
        float ix2 = fminf(mx2, gx2), iy2 = fminf(my2, gy2);
        float iw = fmaxf(ix2 - ix1, 0.0f), ih = fmaxf(iy2 - iy1, 0.0f);
        float inter = iw * ih;
        float uni   = a1 + a2 - inter;
        float iou   = inter / uni;
        float cx1 = fminf(mx1, gx1), cy1 = fminf(my1, gy1);
        float cx2 = fmaxf(mx2, gx2), cy2 = fmaxf(my2, gy2);
        float ac  = fmaxf(cx2 - cx1, 0.0f) * fmaxf(cy2 - cy1, 0.0f);
        lgi = 1.0f - (iou - (ac - uni) / ac);

        int2 tk = tokens[b * NG + g];
        const float* rowp = (const float*)logits + (size_t)(b * NQ + q) * NT;
        for (int t = tk.x; t < tk.y; ++t) dl += focal_delta_term(rowp[t]);
    }
    #pragma unroll
    for (int off = 32; off > 0; off >>= 1) {
        lb  += __shfl_down(lb,  off);
        lgi += __shfl_down(lgi, off);
        dl  += __shfl_down(dl,  off);
    }
    if (lane == 0) {
        ws_store(&ws[WS_BB + b], lb);
        ws_store(&ws[WS_GI + b], lgi);
        ws_store(&ws[WS_DL + b], dl);
    }
}

__device__ void finalize_body(const float* __restrict__ ws,
                              float* __restrict__ out) {
    const int tid  = threadIdx.x;
    const int lane = tid & 63;
    const int wav  = tid >> 6;

    float s_neg = 0.0f;
    for (int i = tid; i < FWAVES; i += 256) s_neg += ws_load(&ws[i]);
    float s_bb = 0.0f, s_gi = 0.0f, s_dl = 0.0f;
    if (tid < NB) {
        s_bb = ws_load(&ws[WS_BB + tid]);
        s_gi = ws_load(&ws[WS_GI + tid]);
        s_dl = ws_load(&ws[WS_DL + tid]);
    }
    #pragma unroll
    for (int off = 32; off > 0; off >>= 1) {
        s_neg += __shfl_down(s_neg, off);
        s_bb  += __shfl_down(s_bb,  off);
        s_gi  += __shfl_down(s_gi,  off);
        s_dl  += __shfl_down(s_dl,  off);
    }
    __shared__ float red[4][4];
    if (lane == 0) {
        red[0][wav] = s_neg; red[1][wav] = s_bb;
        red[2][wav] = s_gi;  red[3][wav] = s_dl;
    }
    __syncthreads();
    if (tid == 0) {
        float neg = red[0][0] + red[0][1] + red[0][2] + red[0][3];
        float bb  = red[1][0] + red[1][1] + red[1][2] + red[1][3];
        float gi  = red[2][0] + red[2][1] + red[2][2] + red[2][3];
        float dlt = red[3][0] + red[3][1] + red[3][2] + red[3][3];
        const float num_boxes = (float)(NB * NG);          // 2560
        float lb = 5.0f * bb / num_boxes;
        float lg = 2.0f * gi / num_boxes;
        float cls_sum = 0.75f * neg + dlt;
        float lc = (cls_sum / (float)(NQ * NT)) / num_boxes;
        out[0] = lb;
        out[1] = lg;
        out[2] = lc;
        out[3] = lb + lg + lc;
    }
}

// ---------------------------------------------------------------------------
// Cooperative single-launch kernel.
// ---------------------------------------------------------------------------
__global__ __launch_bounds__(256, 4) void coop_kernel(
    const float4* __restrict__ logits,
    const float4* __restrict__ pred_boxes,
    const float4* __restrict__ tgt_boxes,
    const int2*   __restrict__ tokens,
    float*        __restrict__ ws,
    float*        __restrict__ out)
{
    __shared__ float4 sbox[NQ];
    __shared__ float  sarea[NQ];

    if (blockIdx.x >= MATCH_BLOCKS) {
        focal_path(logits, ws, blockIdx.x - MATCH_BLOCKS);
    } else {
        match_path(logits, pred_boxes, tgt_boxes, tokens, ws, sbox, sarea,
                   blockIdx.x);
    }

    __threadfence();            // release partials to device scope
    cg::this_grid().sync();
    __threadfence();            // acquire side

    if (blockIdx.x == 0) finalize_body(ws, out);
}

// ---------------------------------------------------------------------------
// Fallback pair (identical math, two launches) — used if coop launch fails.
// ---------------------------------------------------------------------------
__global__ __launch_bounds__(256, 4) void partials_kernel(
    const float4* __restrict__ logits,
    const float4* __restrict__ pred_boxes,
    const float4* __restrict__ tgt_boxes,
    const int2*   __restrict__ tokens,
    float*        __restrict__ ws)
{
    __shared__ float4 sbox[NQ];
    __shared__ float  sarea[NQ];

    if (blockIdx.x >= MATCH_BLOCKS) {
        focal_path(logits, ws, blockIdx.x - MATCH_BLOCKS);
    } else {
        match_path(logits, pred_boxes, tgt_boxes, tokens, ws, sbox, sarea,
                   blockIdx.x);
    }
}

__global__ __launch_bounds__(256) void finalize_kernel(
    const float* __restrict__ ws, float* __restrict__ out)
{
    finalize_body(ws, out);
}

extern "C" void kernel_launch(void* const* d_in, const int* in_sizes, int n_in,
                              void* d_out, int out_size, void* d_ws, size_t ws_size,
                              hipStream_t stream) {
    const float4* pred_logits4 = (const float4*)d_in[0];  // (B,Q,T) f32
    const float4* pred_boxes4  = (const float4*)d_in[1];  // (B,Q,4) f32
    const float4* tgt_boxes4   = (const float4*)d_in[2];  // (B,G,4) f32
    const int2*   tokens2      = (const int2*)d_in[3];    // (B,G,2) i32
    float*        ws           = (float*)d_ws;            // 3712 floats
    float*        outp         = (float*)d_out;

    void* args[] = { (void*)&pred_logits4, (void*)&pred_boxes4,
                     (void*)&tgt_boxes4,   (void*)&tokens2,
                     (void*)&ws,           (void*)&outp };
    hipError_t err = hipLaunchCooperativeKernel((const void*)coop_kernel,
                                                dim3(TOTAL_BLOCKS), dim3(256),
                                                args, 0, stream);
    if (err != hipSuccess) {
        (void)hipGetLastError();   // clear sticky error
        partials_kernel<<<TOTAL_BLOCKS, 256, 0, stream>>>(
            pred_logits4, pred_boxes4, tgt_boxes4, tokens2, ws);
        finalize_kernel<<<1, 256, 0, stream>>>(ws, outp);
    }
}

// Round 7
// 479.120 us; speedup vs baseline: 1.0079x; 1.0079x over previous
//
#include <hip/hip_runtime.h>
#include <hip/hip_bf16.h>

#define NB 128
#define NQ 900
#define NT 256
#define NG 20
#define NR 15                 // pred rows per lane in match: 64*15 >= 900
#define FOCAL_BLOCKS 1800
#define MATCH_BLOCKS 128
#define TOTAL_BLOCKS (FOCAL_BLOCKS + MATCH_BLOCKS)   // 1928
#define FWAVES (FOCAL_BLOCKS * 4)   // 7200 focal waves; 16 rows each = 115200 rows

// ws layout (floats): [0,7200) focal per-wave partials
//   [7200,7328) bbox per-batch, [7328,7456) giou, [7456,7584) delta
//   [7584] (as uint) ticket counter — poison-init 0xAAAAAAAA, self-restoring
#define WS_BB 7200
#define WS_GI 7328
#define WS_DL 7456
#define WS_TICKET 7584
#define TICKET_INIT 0xAAAAAAAAu

__device__ __forceinline__ float clamp01(float v) {
    return fminf(fmaxf(v, 0.0f), 1.0f);
}

// Agent-scope (device-coherent) accesses for cross-XCD partial handoff.
__device__ __forceinline__ void ws_store(float* p, float v) {
    __hip_atomic_store(p, v, __ATOMIC_RELAXED, __HIP_MEMORY_SCOPE_AGENT);
}
__device__ __forceinline__ float ws_load(const float* p) {
    return __hip_atomic_load(p, __ATOMIC_RELAXED, __HIP_MEMORY_SCOPE_AGENT);
}

// focal(x, target=0) WITHOUT the 0.75 alpha (folded into finalize).
__device__ __forceinline__ float focal_neg_term(float x) {
    float ax  = fabsf(x);
    float em  = __expf(-ax);
    float a1  = 1.0f + em;
    float ce  = fmaxf(x, 0.0f) + __logf(a1);
    float inv = __builtin_amdgcn_rcpf(a1);
    float p   = (x >= 0.0f) ? inv : em * inv;
    return ce * p * p;
}

// focal(x,1) - focal(x,0), full alpha factors included.
__device__ __forceinline__ float focal_delta_term(float x) {
    float ax     = fabsf(x);
    float em     = __expf(-ax);
    float a1     = 1.0f + em;
    float lg     = __logf(a1);
    float ce0    = fmaxf(x, 0.0f) + lg;
    float ce1    = ce0 - x;
    float inv    = __builtin_amdgcn_rcpf(a1);
    float em_inv = em * inv;
    float p      = (x >= 0.0f) ? inv : em_inv;   // sigmoid(x)
    float omp    = (x >= 0.0f) ? em_inv : inv;   // 1 - p
    return 0.25f * ce1 * omp * omp - 0.75f * ce0 * p * p;
}

__device__ __forceinline__ float focal_row_sum4(float4 v) {
    return focal_neg_term(v.x) + focal_neg_term(v.y) +
           focal_neg_term(v.z) + focal_neg_term(v.w);
}

// ---------------------------------------------------------------------------
// Single kernel. Blocks [0,128): per-batch greedy match + bbox L1 + GIoU +
// span correction (register-resident boxes, wave 0 only, no early returns).
// Blocks [128,1928): focal(target=0) baseline. Tail: threadfence + ticket
// atomicAdd; the 1928th arrival runs the finalize inline and restores the
// ticket to its poison-init value.
// ---------------------------------------------------------------------------
__global__ __launch_bounds__(256) void main_kernel(
    const float4* __restrict__ logits,      // [B*Q*T/4]
    const float4* __restrict__ pred_boxes,  // [B*Q] cxcywh
    const float4* __restrict__ tgt_boxes,   // [B*G] cxcywh
    const int2*   __restrict__ tokens,      // [B*G] (start, end)
    float*        __restrict__ ws,          // partials + ticket
    float*        __restrict__ out)         // [4]
{
    if (blockIdx.x >= MATCH_BLOCKS) {
        // ----------------- focal(target=0) baseline path -----------------
        const int lane = threadIdx.x & 63;
        const int gw   = ((blockIdx.x - MATCH_BLOCKS) * 256 + (int)threadIdx.x) >> 6;

        float sum = 0.0f;
        #pragma unroll
        for (int i = 0; i < 4; ++i) {
            int row0 = (gw + i * FWAVES) * 4;
            const float4* base = logits + (size_t)row0 * (NT / 4) + lane;
            float4 v0 = base[0 * (NT / 4)];
            float4 v1 = base[1 * (NT / 4)];
            float4 v2 = base[2 * (NT / 4)];
            float4 v3 = base[3 * (NT / 4)];
            sum += focal_row_sum4(v0) + focal_row_sum4(v1) +
                   focal_row_sum4(v2) + focal_row_sum4(v3);
        }
        #pragma unroll
        for (int off = 32; off > 0; off >>= 1) sum += __shfl_down(sum, off);
        if (lane == 0) ws_store(&ws[gw], sum);
    } else if (threadIdx.x < 64) {
        // ----------------- match path: one wave per batch -----------------
        const int b    = blockIdx.x;
        const int lane = threadIdx.x;

        float px1[NR], py1[NR], px2[NR], py2[NR], pa[NR];
        int avail = 0;
        #pragma unroll
        for (int r = 0; r < NR; ++r) {
            int q = lane + 64 * r;
            if (q < NQ) {
                float4 pb = pred_boxes[b * NQ + q];
                px1[r] = pb.x - 0.5f * pb.z; py1[r] = pb.y - 0.5f * pb.w;
                px2[r] = pb.x + 0.5f * pb.z; py2[r] = pb.y + 0.5f * pb.w;
                pa[r]  = (px2[r] - px1[r]) * (py2[r] - py1[r]);
                avail |= (1 << r);
            } else {
                px1[r] = 0.0f; py1[r] = 0.0f; px2[r] = 0.0f; py2[r] = 0.0f;
                pa[r] = 0.0f;
            }
        }

        int my_q = 0;   // matched q for g == lane (lanes 0..19)
        for (int g = 0; g < NG; ++g) {
            float4 tb = tgt_boxes[b * NG + g];          // broadcast load
            float gx1 = tb.x - 0.5f * tb.z, gy1 = tb.y - 0.5f * tb.w;
            float gx2 = tb.x + 0.5f * tb.z, gy2 = tb.y + 0.5f * tb.w;
            float ga  = (gx2 - gx1) * (gy2 - gy1);
            float bv = -2.0f;
            int   bi = 0x7fffffff;
            #pragma unroll
            for (int r = 0; r < NR; ++r) {
                float ix1 = fmaxf(px1[r], gx1), iy1 = fmaxf(py1[r], gy1);
                float ix2 = fminf(px2[r], gx2), iy2 = fminf(py2[r], gy2);
                float iw = fmaxf(ix2 - ix1, 0.0f), ih = fmaxf(iy2 - iy1, 0.0f);
                float inter = iw * ih;
                float v = inter / (pa[r] + ga - inter);   // exact div, matches ref
                bool ok = (avail >> r) & 1;
                v = ok ? v : -1.0f;                       // also kills q>=900 NaNs
                int q = lane + 64 * r;
                if (v > bv) { bv = v; bi = q; }           // strict >: first max
            }
            #pragma unroll
            for (int off = 1; off < 64; off <<= 1) {
                float ov = __shfl_xor(bv, off);
                int   oi = __shfl_xor(bi, off);
                if (ov > bv || (ov == bv && oi < bi)) { bv = ov; bi = oi; }
            }
            if (lane == g) my_q = bi;
            if ((bi & 63) == lane) avail &= ~(1 << (bi >> 6));
        }

        // Epilogue: bbox L1 + GIoU + span correction for g = lane < 20.
        float lb = 0.0f, lgi = 0.0f, dl = 0.0f;
        if (lane < NG) {
            int g = lane, q = my_q;
            float4 pb = pred_boxes[b * NQ + q];
            float4 tb = tgt_boxes[b * NG + g];
            lb = fabsf(pb.x - tb.x) + fabsf(pb.y - tb.y) +
                 fabsf(pb.z - tb.z) + fabsf(pb.w - tb.w);

            float mx1 = pb.x - 0.5f * pb.z, my1 = pb.y - 0.5f * pb.w;
            float mx2 = pb.x + 0.5f * pb.z, my2 = pb.y + 0.5f * pb.w;
            mx2 = fmaxf(mx2, mx1 + 1e-6f);  my2 = fmaxf(my2, my1 + 1e-6f);
            mx1 = clamp01(mx1); my1 = clamp01(my1);
            mx2 = clamp01(mx2); my2 = clamp01(my2);

            float gx1 = tb.x - 0.5f * tb.z, gy1 = tb.y - 0.5f * tb.w;
            float gx2 = tb.x + 0.5f * tb.z, gy2 = tb.y + 0.5f * tb.w;
            gx2 = fmaxf(gx2, gx1 + 1e-6f);  gy2 = fmaxf(gy2, gy1 + 1e-6f);
            gx1 = clamp01(gx1); gy1 = clamp01(gy1);
            gx2 = clamp01(gx2); gy2 = clamp01(gy2);

            float a1 = (mx2 - mx1) * (my2 - my1);
            float a2 = (gx2 - gx1) * (gy2 - gy1);
            float ix1 = fmaxf(mx1, gx1), iy1 = fmaxf(my1, gy1);
            float ix2 = fminf(mx2, gx2), iy2 = fminf(my2, gy2);
            float iw = fmaxf(ix2 - ix1, 0.0f), ih = fmaxf(iy2 - iy1, 0.0f);
            float inter = iw * ih;
            float uni   = a1 + a2 - inter;
            float iou   = inter / uni;
            float cx1 = fminf(mx1, gx1), cy1 = fminf(my1, gy1);
            float cx2 = fmaxf(mx2, gx2), cy2 = fmaxf(my2, gy2);
            float ac  = fmaxf(cx2 - cx1, 0.0f) * fmaxf(cy2 - cy1, 0.0f);
            lgi = 1.0f - (iou - (ac - uni) / ac);

            int2 tk = tokens[b * NG + g];
            const float* rowp = (const float*)logits + (size_t)(b * NQ + q) * NT;
            for (int t = tk.x; t < tk.y; ++t) dl += focal_delta_term(rowp[t]);
        }
        #pragma unroll
        for (int off = 32; off > 0; off >>= 1) {
            lb  += __shfl_down(lb,  off);
            lgi += __shfl_down(lgi, off);
            dl  += __shfl_down(dl,  off);
        }
        if (lane == 0) {
            ws_store(&ws[WS_BB + b], lb);
            ws_store(&ws[WS_GI + b], lgi);
            ws_store(&ws[WS_DL + b], dl);
        }
    }

    // ----------------- last-block ticket + inline finalize -----------------
    __shared__ bool lastFlag;
    unsigned int* ticket = (unsigned int*)&ws[WS_TICKET];

    __threadfence();          // release this block's partial stores
    __syncthreads();          // uniform: no thread returned early
    if (threadIdx.x == 0) {
        unsigned int old = __hip_atomic_fetch_add(
            ticket, 1u, __ATOMIC_ACQ_REL, __HIP_MEMORY_SCOPE_AGENT);
        lastFlag = (old == TICKET_INIT + (unsigned)(TOTAL_BLOCKS - 1));
    }
    __syncthreads();
    if (!lastFlag) return;

    // We are the last block: all 1928 partials are released and visible.
    __threadfence();          // acquire side
    {
        const int tid  = threadIdx.x;
        const int lane = tid & 63;
        const int wav  = tid >> 6;

        float s_neg = 0.0f;
        for (int i = tid; i < FWAVES; i += 256) s_neg += ws_load(&ws[i]);
        float s_bb = 0.0f, s_gi = 0.0f, s_dl = 0.0f;
        if (tid < NB) {
            s_bb = ws_load(&ws[WS_BB + tid]);
            s_gi = ws_load(&ws[WS_GI + tid]);
            s_dl = ws_load(&ws[WS_DL + tid]);
        }
        #pragma unroll
        for (int off = 32; off > 0; off >>= 1) {
            s_neg += __shfl_down(s_neg, off);
            s_bb  += __shfl_down(s_bb,  off);
            s_gi  += __shfl_down(s_gi,  off);
            s_dl  += __shfl_down(s_dl,  off);
        }
        __shared__ float red[4][4];
        if (lane == 0) {
            red[0][wav] = s_neg; red[1][wav] = s_bb;
            red[2][wav] = s_gi;  red[3][wav] = s_dl;
        }
        __syncthreads();
        if (tid == 0) {
            float neg = red[0][0] + red[0][1] + red[0][2] + red[0][3];
            float bb  = red[1][0] + red[1][1] + red[1][2] + red[1][3];
            float gi  = red[2][0] + red[2][1] + red[2][2] + red[2][3];
            float dlt = red[3][0] + red[3][1] + red[3][2] + red[3][3];
            const float num_boxes = (float)(NB * NG);          // 2560
            float lbo = 5.0f * bb / num_boxes;
            float lgo = 2.0f * gi / num_boxes;
            float cls_sum = 0.75f * neg + dlt;
            float lco = (cls_sum / (float)(NQ * NT)) / num_boxes;
            out[0] = lbo;
            out[1] = lgo;
            out[2] = lco;
            out[3] = lbo + lgo + lco;
            // Restore ticket so the scheme also works without re-poison.
            __hip_atomic_store(ticket, TICKET_INIT, __ATOMIC_RELAXED,
                               __HIP_MEMORY_SCOPE_AGENT);
        }
    }
}

extern "C" void kernel_launch(void* const* d_in, const int* in_sizes, int n_in,
                              void* d_out, int out_size, void* d_ws, size_t ws_size,
                              hipStream_t stream) {
    const float4* pred_logits4 = (const float4*)d_in[0];  // (B,Q,T) f32
    const float4* pred_boxes4  = (const float4*)d_in[1];  // (B,Q,4) f32
    const float4* tgt_boxes4   = (const float4*)d_in[2];  // (B,G,4) f32
    const int2*   tokens2      = (const int2*)d_in[3];    // (B,G,2) i32
    float*        ws           = (float*)d_ws;            // 7585 floats used
    float*        outp         = (float*)d_out;

    main_kernel<<<TOTAL_BLOCKS, 256, 0, stream>>>(pred_logits4, pred_boxes4,
                                                  tgt_boxes4, tokens2, ws, outp);
}

// Round 8
// 203.650 us; speedup vs baseline: 2.3713x; 2.3527x over previous
//
#include <hip/hip_runtime.h>
#include <hip/hip_bf16.h>

#define NB 128
#define NQ 900
#define NT 256
#define NG 20
#define NR 15                 // pred rows per lane in match: 64*15 >= 900
#define FOCAL_BLOCKS 1800
#define MATCH_BLOCKS 128
#define TOTAL_BLOCKS (FOCAL_BLOCKS + MATCH_BLOCKS)   // 1928
#define FWAVES (FOCAL_BLOCKS * 4)   // 7200 focal waves; 16 rows each = 115200 rows

// ws layout (floats): [0]=bbox acc, [1]=giou acc, [2]=focal-neg acc,
// [3]=delta acc, [4]=(uint) ticket. All poison-init 0xAAAAAAAA
// (poison float = -3.03e-13 — negligible offset on the accumulators);
// finalize restores the poison pattern for robustness.
#define WS_TICKET 4
#define TICKET_INIT 0xAAAAAAAAu

__device__ __forceinline__ float clamp01(float v) {
    return fminf(fmaxf(v, 0.0f), 1.0f);
}

// Relaxed agent-scope RMW/load — coherence-point ops, NO fences (no wbl2/inv).
__device__ __forceinline__ float acc_add(float* p, float v) {
    return __hip_atomic_fetch_add(p, v, __ATOMIC_RELAXED, __HIP_MEMORY_SCOPE_AGENT);
}
__device__ __forceinline__ float acc_load(const float* p) {
    return __hip_atomic_load(p, __ATOMIC_RELAXED, __HIP_MEMORY_SCOPE_AGENT);
}

// focal(x, target=0) WITHOUT the 0.75 alpha (folded into finalize).
__device__ __forceinline__ float focal_neg_term(float x) {
    float ax  = fabsf(x);
    float em  = __expf(-ax);
    float a1  = 1.0f + em;
    float ce  = fmaxf(x, 0.0f) + __logf(a1);
    float inv = __builtin_amdgcn_rcpf(a1);
    float p   = (x >= 0.0f) ? inv : em * inv;
    return ce * p * p;
}

// focal(x,1) - focal(x,0), full alpha factors included.
__device__ __forceinline__ float focal_delta_term(float x) {
    float ax     = fabsf(x);
    float em     = __expf(-ax);
    float a1     = 1.0f + em;
    float lg     = __logf(a1);
    float ce0    = fmaxf(x, 0.0f) + lg;
    float ce1    = ce0 - x;
    float inv    = __builtin_amdgcn_rcpf(a1);
    float em_inv = em * inv;
    float p      = (x >= 0.0f) ? inv : em_inv;   // sigmoid(x)
    float omp    = (x >= 0.0f) ? em_inv : inv;   // 1 - p
    return 0.25f * ce1 * omp * omp - 0.75f * ce0 * p * p;
}

__device__ __forceinline__ float focal_row_sum4(float4 v) {
    return focal_neg_term(v.x) + focal_neg_term(v.y) +
           focal_neg_term(v.z) + focal_neg_term(v.w);
}

// Single-thread finalize: read the 4 accumulators (agent-scope atomic loads,
// issued after the ticket RMW returned the final count), write d_out,
// restore poison.
__device__ void finalize(float* __restrict__ ws, float* __restrict__ out) {
    float bb  = acc_load(&ws[0]);
    float gi  = acc_load(&ws[1]);
    float neg = acc_load(&ws[2]);
    float dlt = acc_load(&ws[3]);
    const float num_boxes = (float)(NB * NG);          // 2560
    float lbo = 5.0f * bb / num_boxes;
    float lgo = 2.0f * gi / num_boxes;
    float cls_sum = 0.75f * neg + dlt;
    float lco = (cls_sum / (float)(NQ * NT)) / num_boxes;
    out[0] = lbo;
    out[1] = lgo;
    out[2] = lco;
    out[3] = lbo + lgo + lco;
    // Restore poison pattern so repeat calls without re-poison also work.
    unsigned int* wsu = (unsigned int*)ws;
    __hip_atomic_store(&wsu[0], TICKET_INIT, __ATOMIC_RELAXED, __HIP_MEMORY_SCOPE_AGENT);
    __hip_atomic_store(&wsu[1], TICKET_INIT, __ATOMIC_RELAXED, __HIP_MEMORY_SCOPE_AGENT);
    __hip_atomic_store(&wsu[2], TICKET_INIT, __ATOMIC_RELAXED, __HIP_MEMORY_SCOPE_AGENT);
    __hip_atomic_store(&wsu[3], TICKET_INIT, __ATOMIC_RELAXED, __HIP_MEMORY_SCOPE_AGENT);
    __hip_atomic_store(&wsu[WS_TICKET], TICKET_INIT, __ATOMIC_RELAXED, __HIP_MEMORY_SCOPE_AGENT);
}

// ---------------------------------------------------------------------------
// Fence-free single kernel. Blocks [0,128): per-batch greedy match + bbox L1
// + GIoU + span correction (register-resident, wave 0 only). Blocks
// [128,1928): focal(target=0) baseline. Each block: relaxed agent fetch_add
// of its partial(s), then ticket fetch_add whose increment phantom-depends
// (inline asm) on the partial RMW's return — ordering without any fence.
// Last arrival finalizes inline.
// ---------------------------------------------------------------------------
__global__ __launch_bounds__(256) void main_kernel(
    const float4* __restrict__ logits,      // [B*Q*T/4]
    const float4* __restrict__ pred_boxes,  // [B*Q] cxcywh
    const float4* __restrict__ tgt_boxes,   // [B*G] cxcywh
    const int2*   __restrict__ tokens,      // [B*G] (start, end)
    float*        __restrict__ ws,          // acc[4] + ticket
    float*        __restrict__ out)         // [4]
{
    unsigned int* ticket = (unsigned int*)ws + WS_TICKET;

    if (blockIdx.x >= MATCH_BLOCKS) {
        // ----------------- focal(target=0) baseline path -----------------
        const int lane = threadIdx.x & 63;
        const int wav  = threadIdx.x >> 6;
        const int gw   = ((blockIdx.x - MATCH_BLOCKS) * 256 + (int)threadIdx.x) >> 6;

        float sum = 0.0f;
        #pragma unroll
        for (int i = 0; i < 4; ++i) {
            int row0 = (gw + i * FWAVES) * 4;
            const float4* base = logits + (size_t)row0 * (NT / 4) + lane;
            float4 v0 = base[0 * (NT / 4)];
            float4 v1 = base[1 * (NT / 4)];
            float4 v2 = base[2 * (NT / 4)];
            float4 v3 = base[3 * (NT / 4)];
            sum += focal_row_sum4(v0) + focal_row_sum4(v1) +
                   focal_row_sum4(v2) + focal_row_sum4(v3);
        }
        #pragma unroll
        for (int off = 32; off > 0; off >>= 1) sum += __shfl_down(sum, off);

        __shared__ float wsum[4];
        if (lane == 0) wsum[wav] = sum;
        __syncthreads();
        if (threadIdx.x == 0) {
            float tot = wsum[0] + wsum[1] + wsum[2] + wsum[3];
            float o = acc_add(&ws[2], tot);
            unsigned inc;
            // inc = 1, with a phantom data dependency on the RMW return:
            // forces s_waitcnt on o before the ticket atomic issues.
            asm volatile("v_mov_b32 %0, 1" : "=v"(inc) : "v"(o));
            unsigned old = __hip_atomic_fetch_add(
                ticket, inc, __ATOMIC_RELAXED, __HIP_MEMORY_SCOPE_AGENT);
            if (old == TICKET_INIT + (unsigned)(TOTAL_BLOCKS - 1))
                finalize(ws, out);
        }
        return;
    }

    // ----------------- match path: one wave per batch -----------------
    if (threadIdx.x >= 64) return;
    const int b    = blockIdx.x;
    const int lane = threadIdx.x;

    float px1[NR], py1[NR], px2[NR], py2[NR], pa[NR];
    int avail = 0;
    #pragma unroll
    for (int r = 0; r < NR; ++r) {
        int q = lane + 64 * r;
        if (q < NQ) {
            float4 pb = pred_boxes[b * NQ + q];
            px1[r] = pb.x - 0.5f * pb.z; py1[r] = pb.y - 0.5f * pb.w;
            px2[r] = pb.x + 0.5f * pb.z; py2[r] = pb.y + 0.5f * pb.w;
            pa[r]  = (px2[r] - px1[r]) * (py2[r] - py1[r]);
            avail |= (1 << r);
        } else {
            px1[r] = 0.0f; py1[r] = 0.0f; px2[r] = 0.0f; py2[r] = 0.0f;
            pa[r] = 0.0f;
        }
    }

    int my_q = 0;   // matched q for g == lane (lanes 0..19)
    for (int g = 0; g < NG; ++g) {
        float4 tb = tgt_boxes[b * NG + g];          // broadcast load
        float gx1 = tb.x - 0.5f * tb.z, gy1 = tb.y - 0.5f * tb.w;
        float gx2 = tb.x + 0.5f * tb.z, gy2 = tb.y + 0.5f * tb.w;
        float ga  = (gx2 - gx1) * (gy2 - gy1);
        float bv = -2.0f;
        int   bi = 0x7fffffff;
        #pragma unroll
        for (int r = 0; r < NR; ++r) {
            float ix1 = fmaxf(px1[r], gx1), iy1 = fmaxf(py1[r], gy1);
            float ix2 = fminf(px2[r], gx2), iy2 = fminf(py2[r], gy2);
            float iw = fmaxf(ix2 - ix1, 0.0f), ih = fmaxf(iy2 - iy1, 0.0f);
            float inter = iw * ih;
            float v = inter / (pa[r] + ga - inter);   // exact div, matches ref
            bool ok = (avail >> r) & 1;
            v = ok ? v : -1.0f;                       // also kills q>=900 NaNs
            int q = lane + 64 * r;
            if (v > bv) { bv = v; bi = q; }           // strict >: first max
        }
        #pragma unroll
        for (int off = 1; off < 64; off <<= 1) {
            float ov = __shfl_xor(bv, off);
            int   oi = __shfl_xor(bi, off);
            if (ov > bv || (ov == bv && oi < bi)) { bv = ov; bi = oi; }
        }
        if (lane == g) my_q = bi;
        if ((bi & 63) == lane) avail &= ~(1 << (bi >> 6));
    }

    // Epilogue: bbox L1 + GIoU + span correction for g = lane < 20.
    float lb = 0.0f, lgi = 0.0f, dl = 0.0f;
    if (lane < NG) {
        int g = lane, q = my_q;
        float4 pb = pred_boxes[b * NQ + q];
        float4 tb = tgt_boxes[b * NG + g];
        lb = fabsf(pb.x - tb.x) + fabsf(pb.y - tb.y) +
             fabsf(pb.z - tb.z) + fabsf(pb.w - tb.w);

        float mx1 = pb.x - 0.5f * pb.z, my1 = pb.y - 0.5f * pb.w;
        float mx2 = pb.x + 0.5f * pb.z, my2 = pb.y + 0.5f * pb.w;
        mx2 = fmaxf(mx2, mx1 + 1e-6f);  my2 = fmaxf(my2, my1 + 1e-6f);
        mx1 = clamp01(mx1); my1 = clamp01(my1);
        mx2 = clamp01(mx2); my2 = clamp01(my2);

        float gx1 = tb.x - 0.5f * tb.z, gy1 = tb.y - 0.5f * tb.w;
        float gx2 = tb.x + 0.5f * tb.z, gy2 = tb.y + 0.5f * tb.w;
        gx2 = fmaxf(gx2, gx1 + 1e-6f);  gy2 = fmaxf(gy2, gy1 + 1e-6f);
        gx1 = clamp01(gx1); gy1 = clamp01(gy1);
        gx2 = clamp01(gx2); gy2 = clamp01(gy2);

        float a1 = (mx2 - mx1) * (my2 - my1);
        float a2 = (gx2 - gx1) * (gy2 - gy1);
        float ix1 = fmaxf(mx1, gx1), iy1 = fmaxf(my1, gy1);
        float ix2 = fminf(mx2, gx2), iy2 = fminf(my2, gy2);
        float iw = fmaxf(ix2 - ix1, 0.0f), ih = fmaxf(iy2 - iy1, 0.0f);
        float inter = iw * ih;
        float uni   = a1 + a2 - inter;
        float iou   = inter / uni;
        float cx1 = fminf(mx1, gx1), cy1 = fminf(my1, gy1);
        float cx2 = fmaxf(mx2, gx2), cy2 = fmaxf(my2, gy2);
        float ac  = fmaxf(cx2 - cx1, 0.0f) * fmaxf(cy2 - cy1, 0.0f);
        lgi = 1.0f - (iou - (ac - uni) / ac);

        int2 tk = tokens[b * NG + g];
        const float* rowp = (const float*)logits + (size_t)(b * NQ + q) * NT;
        for (int t = tk.x; t < tk.y; ++t) dl += focal_delta_term(rowp[t]);
    }
    #pragma unroll
    for (int off = 32; off > 0; off >>= 1) {
        lb  += __shfl_down(lb,  off);
        lgi += __shfl_down(lgi, off);
        dl  += __shfl_down(dl,  off);
    }
    if (lane == 0) {
        float o0 = acc_add(&ws[0], lb);
        float o1 = acc_add(&ws[1], lgi);
        float o2 = acc_add(&ws[3], dl);
        unsigned inc;
        // inc = 1, phantom-dependent on all three RMW returns.
        asm volatile("v_mov_b32 %0, 1" : "=v"(inc) : "v"(o0), "v"(o1), "v"(o2));
        unsigned old = __hip_atomic_fetch_add(
            ticket, inc, __ATOMIC_RELAXED, __HIP_MEMORY_SCOPE_AGENT);
        if (old == TICKET_INIT + (unsigned)(TOTAL_BLOCKS - 1))
            finalize(ws, out);
    }
}

extern "C" void kernel_launch(void* const* d_in, const int* in_sizes, int n_in,
                              void* d_out, int out_size, void* d_ws, size_t ws_size,
                              hipStream_t stream) {
    const float4* pred_logits4 = (const float4*)d_in[0];  // (B,Q,T) f32
    const float4* pred_boxes4  = (const float4*)d_in[1];  // (B,Q,4) f32
    const float4* tgt_boxes4   = (const float4*)d_in[2];  // (B,G,4) f32
    const int2*   tokens2      = (const int2*)d_in[3];    // (B,G,2) i32
    float*        ws           = (float*)d_ws;            // 5 floats used
    float*        outp         = (float*)d_out;

    main_kernel<<<TOTAL_BLOCKS, 256, 0, stream>>>(pred_logits4, pred_boxes4,
                                                  tgt_boxes4, tokens2, ws, outp);
}